// Round 2
// baseline (779.709 us; speedup 1.0000x reference)
//
#include <hip/hip_runtime.h>
#include <math.h>

#define MIN_NORM 1e-15f
#define MAXN     0.996f          // (1 - 4e-3)/sqrt(c), c=1
#define ATC      0.9999999f      // artanh clip = 1 - 1e-7

__device__ __forceinline__ float fast_artanh(float v) {
    v = fminf(fmaxf(v, -ATC), ATC);
    return 0.5f * __logf((1.0f + v) / (1.0f - v));
}
__device__ __forceinline__ float fast_tanh(float xv) {
    float e2 = __expf(2.0f * xv);
    return (e2 - 1.0f) / (e2 + 1.0f);
}
__device__ __forceinline__ float reduce16(float v) {
    v += __shfl_xor(v, 1);
    v += __shfl_xor(v, 2);
    v += __shfl_xor(v, 4);
    v += __shfl_xor(v, 8);
    return v;
}

// ---- kernel 1: fused HypLinear + logmap0. One wave per row, x in registers. --
__global__ __launch_bounds__(256) void hgcn_k1(
    const float* __restrict__ x, const float* __restrict__ weight,
    const float* __restrict__ bias, float* __restrict__ xt, int N)
{
    const int tid  = threadIdx.x;
    const int lane = tid & 63;
    const int wib  = tid >> 6;           // wave in block (0..3)
    const int k    = lane & 15;

    // W fragment in registers: wr[kk][jj] = W[kk][lane*8 + jj]
    float wr[16][8];
    const float* wp = weight + lane * 8;
#pragma unroll
    for (int kk = 0; kk < 16; ++kk) {
        float4 a = *(const float4*)(wp + kk * 512);
        float4 b = *(const float4*)(wp + kk * 512 + 4);
        wr[kk][0] = a.x; wr[kk][1] = a.y; wr[kk][2] = a.z; wr[kk][3] = a.w;
        wr[kk][4] = b.x; wr[kk][5] = b.y; wr[kk][6] = b.z; wr[kk][7] = b.w;
    }

    // hyp_bias = proj(expmap0(bias)) — replicated per 16-lane group
    float bb = bias[k];
    float b2 = reduce16(bb * bb);
    float bn = fmaxf(sqrtf(b2), MIN_NORM);
    float eb = fast_tanh(bn) * bb / bn;
    float e2 = reduce16(eb * eb);
    float en = fmaxf(sqrtf(e2), MIN_NORM);
    float hb = (en > MAXN) ? eb * (MAXN / en) : eb;
    float y2 = reduce16(hb * hb);

    const long long wstride = (long long)gridDim.x * 4;
    long long row = (long long)blockIdx.x * 4 + wib;

    float4 c0, c1;
    if (row < N) {
        const float* xr = x + row * 512 + lane * 8;
        c0 = *(const float4*)(xr);
        c1 = *(const float4*)(xr + 4);
    }

    while (row < N) {
        long long nrow = row + wstride;
        float4 n0, n1;
        if (nrow < N) {                  // prefetch next row (double buffer)
            const float* xr = x + nrow * 512 + lane * 8;
            n0 = *(const float4*)(xr);
            n1 = *(const float4*)(xr + 4);
        }

        float xv[8] = {c0.x, c0.y, c0.z, c0.w, c1.x, c1.y, c1.z, c1.w};

        // ||x||^2 over all 64 lanes
        float p = 0.0f;
#pragma unroll
        for (int jj = 0; jj < 8; ++jj) p = fmaf(xv[jj], xv[jj], p);
#pragma unroll
        for (int m = 1; m <= 32; m <<= 1) p += __shfl_xor(p, m);
        const float x2 = p;

        // per-lane partial dots for all 16 outputs
        float acc[16];
#pragma unroll
        for (int kk = 0; kk < 16; ++kk) {
            float s = 0.0f;
#pragma unroll
            for (int jj = 0; jj < 8; ++jj) s = fmaf(wr[kk][jj], xv[jj], s);
            acc[kk] = s;
        }

        // value-halving butterfly: k's total lands on lanes with (lane&15)==k
        float v8[8];
        {
            const bool h = lane & 1;
#pragma unroll
            for (int i = 0; i < 8; ++i) {
                float keep = h ? acc[2*i+1] : acc[2*i];
                float give = h ? acc[2*i]   : acc[2*i+1];
                v8[i] = keep + __shfl_xor(give, 1);
            }
        }
        float v4[4];
        {
            const bool h = lane & 2;
#pragma unroll
            for (int i = 0; i < 4; ++i) {
                float keep = h ? v8[2*i+1] : v8[2*i];
                float give = h ? v8[2*i]   : v8[2*i+1];
                v4[i] = keep + __shfl_xor(give, 2);
            }
        }
        float v2[2];
        {
            const bool h = lane & 4;
#pragma unroll
            for (int i = 0; i < 2; ++i) {
                float keep = h ? v4[2*i+1] : v4[2*i];
                float give = h ? v4[2*i]   : v4[2*i+1];
                v2[i] = keep + __shfl_xor(give, 4);
            }
        }
        float mx;
        {
            const bool h = lane & 8;
            float keep = h ? v2[1] : v2[0];
            float give = h ? v2[0] : v2[1];
            mx = keep + __shfl_xor(give, 8);
        }
        mx += __shfl_xor(mx, 16);
        mx += __shfl_xor(mx, 32);

        // ---- Möbius tail (replicated across the four 16-lane groups) ----
        float mx2 = reduce16(mx * mx);
        float xn  = fmaxf(sqrtf(x2),  MIN_NORM);
        float mxn = fmaxf(sqrtf(mx2), MIN_NORM);
        float res = fast_tanh(mxn / xn * fast_artanh(xn)) * mx / mxn;
        if (mx2 == 0.0f) res = 0.0f;
        // proj
        float rn2 = reduce16(res * res);
        float rn  = fmaxf(sqrtf(rn2), MIN_NORM);
        float mv  = (rn > MAXN) ? res * (MAXN / rn) : res;
        // mobius_add(mv, hyp_bias)
        float mv2 = reduce16(mv * mv);
        float xy  = reduce16(mv * hb);
        float num = (1.0f + 2.0f * xy + y2) * mv + (1.0f - mv2) * hb;
        float den = 1.0f + 2.0f * xy + mv2 * y2;
        float hq  = num / fmaxf(den, MIN_NORM);
        // proj
        float hn2 = reduce16(hq * hq);
        float hn  = fmaxf(sqrtf(hn2), MIN_NORM);
        float hp  = (hn > MAXN) ? hq * (MAXN / hn) : hq;
        // logmap0
        float hp2 = reduce16(hp * hp);
        float pn  = fmaxf(sqrtf(hp2), MIN_NORM);
        float xtv = fast_artanh(pn) * hp / pn;

        if (lane < 16) xt[row * 16 + lane] = xtv;

        c0 = n0; c1 = n1;
        row = nrow;
    }
}

// ---------------- index width detection ----------------
__global__ void hgcn_k_detect(const void* srcp, long long E, int* flag)
{
    const int tid = threadIdx.x;
    if (tid == 0) *flag = 0;
    __syncthreads();
    long long n = E / 2; if (n > 4096) n = 4096;
    int bad = 0;
    const unsigned long long* p = (const unsigned long long*)srcp;
    for (long long i = tid; i < n; i += 256)
        if (p[i] >= (1ULL << 32)) bad = 1;
    if (bad) atomicOr(flag, 1);
}

// ---- kernel 2: edge scatter-add, 4 lanes per edge, float4 gather ----
__global__ __launch_bounds__(256) void hgcn_k2(
    const void* __restrict__ srcp, const void* __restrict__ dstp,
    const float* __restrict__ ew, const float* __restrict__ xt,
    float* __restrict__ agg, long long E, const int* __restrict__ flag)
{
    long long gid = (long long)blockIdx.x * 256 + threadIdx.x;
    long long e = gid >> 2;
    int q = (int)(gid & 3);
    if (e >= E) return;
    long long s, d;
    if (*flag) {
        s = ((const int*)srcp)[e];
        d = ((const int*)dstp)[e];
    } else {
        s = ((const long long*)srcp)[e];
        d = ((const long long*)dstp)[e];
    }
    float w = ew[e];
    float4 v = ((const float4*)xt)[s * 4 + q];
    float* dst = agg + d * 16 + q * 4;
    atomicAdd(dst + 0, w * v.x);
    atomicAdd(dst + 1, w * v.y);
    atomicAdd(dst + 2, w * v.z);
    atomicAdd(dst + 3, w * v.w);
}

// ---------------- kernel 3: finalize in place on d_out -----------------------
__global__ __launch_bounds__(256) void hgcn_k3(float* __restrict__ out, int N)
{
    int gid = blockIdx.x * blockDim.x + threadIdx.x;
    int row = gid >> 4;
    if (row >= N) return;
    float u = out[(size_t)row * 16 + (gid & 15)];

    float un2 = reduce16(u * u);
    float un  = fmaxf(sqrtf(un2), MIN_NORM);
    float h1  = fast_tanh(un) * u / un;
    float n2  = reduce16(h1 * h1);
    float n1  = fmaxf(sqrtf(n2), MIN_NORM);
    float h1p = (n1 > MAXN) ? h1 * (MAXN / n1) : h1;
    float m2  = reduce16(h1p * h1p);
    float pn  = fmaxf(sqrtf(m2), MIN_NORM);
    float xt2 = fast_artanh(pn) * h1p / pn;
    float a2  = reduce16(xt2 * xt2);
    float an  = fmaxf(sqrtf(a2), MIN_NORM);
    float h2  = fast_tanh(an) * xt2 / an;
    float b2  = reduce16(h2 * h2);
    float bn  = fmaxf(sqrtf(b2), MIN_NORM);
    float h2p = (bn > MAXN) ? h2 * (MAXN / bn) : h2;
    float c2  = reduce16(h2p * h2p);
    float cn  = fmaxf(sqrtf(c2), MIN_NORM);
    out[(size_t)row * 16 + (gid & 15)] = fast_artanh(cn) * h2p / cn;
}

extern "C" void kernel_launch(void* const* d_in, const int* in_sizes, int n_in,
                              void* d_out, int out_size, void* d_ws, size_t ws_size,
                              hipStream_t stream)
{
    const float* x        = (const float*)d_in[0];
    const float* weight   = (const float*)d_in[1];
    const float* bias     = (const float*)d_in[2];
    const float* edge_w   = (const float*)d_in[3];
    const void*  edge_src = d_in[4];
    const void*  edge_dst = d_in[5];

    const int Kv = in_sizes[2];          // 16
    const int Dv = in_sizes[1] / Kv;     // 512
    const int N  = in_sizes[0] / Dv;     // 100000
    const long long E = in_sizes[3];     // 3200000

    int*   flag = (int*)d_ws;
    float* xt   = (float*)((char*)d_ws + 256);
    float* agg  = (float*)d_out;

    hipMemsetAsync(d_out, 0, (size_t)N * 16 * sizeof(float), stream);
    hipLaunchKernelGGL(hgcn_k_detect, dim3(1), dim3(256), 0, stream, edge_src, E, flag);
    hipLaunchKernelGGL(hgcn_k1, dim3(1024), dim3(256), 0, stream,
                       x, weight, bias, xt, N);
    long long thr = E * 4;
    hipLaunchKernelGGL(hgcn_k2, dim3((unsigned)((thr + 255) / 256)), dim3(256), 0, stream,
                       edge_src, edge_dst, edge_w, xt, agg, E, flag);
    hipLaunchKernelGGL(hgcn_k3, dim3((unsigned)(((long long)N * 16 + 255) / 256)), dim3(256), 0, stream,
                       agg, N);
}

// Round 3
// 311.313 us; speedup vs baseline: 2.5046x; 2.5046x over previous
//
#include <hip/hip_runtime.h>
#include <math.h>

#define MIN_NORM 1e-15f
#define MAXN     0.996f          // (1 - 4e-3)/sqrt(c), c=1
#define ATC      0.9999999f      // artanh clip = 1 - 1e-7

__device__ __forceinline__ float fast_artanh(float v) {
    v = fminf(fmaxf(v, -ATC), ATC);
    return 0.5f * __logf((1.0f + v) / (1.0f - v));
}
__device__ __forceinline__ float fast_tanh(float xv) {
    float e2 = __expf(2.0f * xv);
    return (e2 - 1.0f) / (e2 + 1.0f);
}
__device__ __forceinline__ float reduce16(float v) {
    v += __shfl_xor(v, 1);
    v += __shfl_xor(v, 2);
    v += __shfl_xor(v, 4);
    v += __shfl_xor(v, 8);
    return v;
}

// ---- kernel 1: fused HypLinear + logmap0. One wave per row, x in registers. --
__global__ __launch_bounds__(256) void hgcn_k1(
    const float* __restrict__ x, const float* __restrict__ weight,
    const float* __restrict__ bias, float* __restrict__ xt, int N)
{
    const int tid  = threadIdx.x;
    const int lane = tid & 63;
    const int wib  = tid >> 6;           // wave in block (0..3)
    const int k    = lane & 15;

    // W fragment in registers: wr[kk][jj] = W[kk][lane*8 + jj]
    float wr[16][8];
    const float* wp = weight + lane * 8;
#pragma unroll
    for (int kk = 0; kk < 16; ++kk) {
        float4 a = *(const float4*)(wp + kk * 512);
        float4 b = *(const float4*)(wp + kk * 512 + 4);
        wr[kk][0] = a.x; wr[kk][1] = a.y; wr[kk][2] = a.z; wr[kk][3] = a.w;
        wr[kk][4] = b.x; wr[kk][5] = b.y; wr[kk][6] = b.z; wr[kk][7] = b.w;
    }

    // hyp_bias = proj(expmap0(bias)) — replicated per 16-lane group
    float bb = bias[k];
    float b2 = reduce16(bb * bb);
    float bn = fmaxf(sqrtf(b2), MIN_NORM);
    float eb = fast_tanh(bn) * bb / bn;
    float e2 = reduce16(eb * eb);
    float en = fmaxf(sqrtf(e2), MIN_NORM);
    float hb = (en > MAXN) ? eb * (MAXN / en) : eb;
    float y2 = reduce16(hb * hb);

    const long long wstride = (long long)gridDim.x * 4;
    long long row = (long long)blockIdx.x * 4 + wib;

    float4 c0, c1;
    if (row < N) {
        const float* xr = x + row * 512 + lane * 8;
        c0 = *(const float4*)(xr);
        c1 = *(const float4*)(xr + 4);
    }

    while (row < N) {
        long long nrow = row + wstride;
        float4 n0, n1;
        if (nrow < N) {                  // prefetch next row (double buffer)
            const float* xr = x + nrow * 512 + lane * 8;
            n0 = *(const float4*)(xr);
            n1 = *(const float4*)(xr + 4);
        }

        float xv[8] = {c0.x, c0.y, c0.z, c0.w, c1.x, c1.y, c1.z, c1.w};

        // ||x||^2 over all 64 lanes
        float p = 0.0f;
#pragma unroll
        for (int jj = 0; jj < 8; ++jj) p = fmaf(xv[jj], xv[jj], p);
#pragma unroll
        for (int m = 1; m <= 32; m <<= 1) p += __shfl_xor(p, m);
        const float x2 = p;

        // per-lane partial dots for all 16 outputs
        float acc[16];
#pragma unroll
        for (int kk = 0; kk < 16; ++kk) {
            float s = 0.0f;
#pragma unroll
            for (int jj = 0; jj < 8; ++jj) s = fmaf(wr[kk][jj], xv[jj], s);
            acc[kk] = s;
        }

        // value-halving butterfly: k's total lands on lanes with (lane&15)==k
        float v8[8];
        {
            const bool h = lane & 1;
#pragma unroll
            for (int i = 0; i < 8; ++i) {
                float keep = h ? acc[2*i+1] : acc[2*i];
                float give = h ? acc[2*i]   : acc[2*i+1];
                v8[i] = keep + __shfl_xor(give, 1);
            }
        }
        float v4[4];
        {
            const bool h = lane & 2;
#pragma unroll
            for (int i = 0; i < 4; ++i) {
                float keep = h ? v8[2*i+1] : v8[2*i];
                float give = h ? v8[2*i]   : v8[2*i+1];
                v4[i] = keep + __shfl_xor(give, 2);
            }
        }
        float v2[2];
        {
            const bool h = lane & 4;
#pragma unroll
            for (int i = 0; i < 2; ++i) {
                float keep = h ? v4[2*i+1] : v4[2*i];
                float give = h ? v4[2*i]   : v4[2*i+1];
                v2[i] = keep + __shfl_xor(give, 4);
            }
        }
        float mx;
        {
            const bool h = lane & 8;
            float keep = h ? v2[1] : v2[0];
            float give = h ? v2[0] : v2[1];
            mx = keep + __shfl_xor(give, 8);
        }
        mx += __shfl_xor(mx, 16);
        mx += __shfl_xor(mx, 32);

        // ---- Möbius tail (replicated across the four 16-lane groups) ----
        float mx2 = reduce16(mx * mx);
        float xn  = fmaxf(sqrtf(x2),  MIN_NORM);
        float mxn = fmaxf(sqrtf(mx2), MIN_NORM);
        float res = fast_tanh(mxn / xn * fast_artanh(xn)) * mx / mxn;
        if (mx2 == 0.0f) res = 0.0f;
        // proj
        float rn2 = reduce16(res * res);
        float rn  = fmaxf(sqrtf(rn2), MIN_NORM);
        float mv  = (rn > MAXN) ? res * (MAXN / rn) : res;
        // mobius_add(mv, hyp_bias)
        float mv2 = reduce16(mv * mv);
        float xy  = reduce16(mv * hb);
        float num = (1.0f + 2.0f * xy + y2) * mv + (1.0f - mv2) * hb;
        float den = 1.0f + 2.0f * xy + mv2 * y2;
        float hq  = num / fmaxf(den, MIN_NORM);
        // proj
        float hn2 = reduce16(hq * hq);
        float hn  = fmaxf(sqrtf(hn2), MIN_NORM);
        float hp  = (hn > MAXN) ? hq * (MAXN / hn) : hq;
        // logmap0
        float hp2 = reduce16(hp * hp);
        float pn  = fmaxf(sqrtf(hp2), MIN_NORM);
        float xtv = fast_artanh(pn) * hp / pn;

        if (lane < 16) xt[row * 16 + lane] = xtv;

        c0 = n0; c1 = n1;
        row = nrow;
    }
}

// ---------------- index width detection ----------------
__global__ void hgcn_k_detect(const void* srcp, long long E, int* flag)
{
    const int tid = threadIdx.x;
    if (tid == 0) *flag = 0;
    __syncthreads();
    long long n = E / 2; if (n > 4096) n = 4096;
    int bad = 0;
    const unsigned long long* p = (const unsigned long long*)srcp;
    for (long long i = tid; i < n; i += 256)
        if (p[i] >= (1ULL << 32)) bad = 1;
    if (bad) atomicOr(flag, 1);
}

// ---- kernel 2: edge scatter-add, 16 lanes per edge ----
// 16 consecutive lanes hit 16 consecutive dwords of one destination row
// (64B-aligned line) -> TCC merges each group into one line-atomic.
__global__ __launch_bounds__(256) void hgcn_k2(
    const void* __restrict__ srcp, const void* __restrict__ dstp,
    const float* __restrict__ ew, const float* __restrict__ xt,
    float* __restrict__ agg, long long E, const int* __restrict__ flag)
{
    long long gid = (long long)blockIdx.x * 256 + threadIdx.x;
    long long e = gid >> 4;
    int k = (int)(gid & 15);
    if (e >= E) return;
    long long s, d;
    if (*flag) {
        s = ((const int*)srcp)[e];
        d = ((const int*)dstp)[e];
    } else {
        s = ((const long long*)srcp)[e];
        d = ((const long long*)dstp)[e];
    }
    float w = ew[e];
    atomicAdd(&agg[d * 16 + k], w * xt[s * 16 + k]);
}

// ---------------- kernel 3: finalize in place on d_out -----------------------
__global__ __launch_bounds__(256) void hgcn_k3(float* __restrict__ out, int N)
{
    int gid = blockIdx.x * blockDim.x + threadIdx.x;
    int row = gid >> 4;
    if (row >= N) return;
    float u = out[(size_t)row * 16 + (gid & 15)];

    float un2 = reduce16(u * u);
    float un  = fmaxf(sqrtf(un2), MIN_NORM);
    float h1  = fast_tanh(un) * u / un;
    float n2  = reduce16(h1 * h1);
    float n1  = fmaxf(sqrtf(n2), MIN_NORM);
    float h1p = (n1 > MAXN) ? h1 * (MAXN / n1) : h1;
    float m2  = reduce16(h1p * h1p);
    float pn  = fmaxf(sqrtf(m2), MIN_NORM);
    float xt2 = fast_artanh(pn) * h1p / pn;
    float a2  = reduce16(xt2 * xt2);
    float an  = fmaxf(sqrtf(a2), MIN_NORM);
    float h2  = fast_tanh(an) * xt2 / an;
    float b2  = reduce16(h2 * h2);
    float bn  = fmaxf(sqrtf(b2), MIN_NORM);
    float h2p = (bn > MAXN) ? h2 * (MAXN / bn) : h2;
    float c2  = reduce16(h2p * h2p);
    float cn  = fmaxf(sqrtf(c2), MIN_NORM);
    out[(size_t)row * 16 + (gid & 15)] = fast_artanh(cn) * h2p / cn;
}

extern "C" void kernel_launch(void* const* d_in, const int* in_sizes, int n_in,
                              void* d_out, int out_size, void* d_ws, size_t ws_size,
                              hipStream_t stream)
{
    const float* x        = (const float*)d_in[0];
    const float* weight   = (const float*)d_in[1];
    const float* bias     = (const float*)d_in[2];
    const float* edge_w   = (const float*)d_in[3];
    const void*  edge_src = d_in[4];
    const void*  edge_dst = d_in[5];

    const int Kv = in_sizes[2];          // 16
    const int Dv = in_sizes[1] / Kv;     // 512
    const int N  = in_sizes[0] / Dv;     // 100000
    const long long E = in_sizes[3];     // 3200000

    int*   flag = (int*)d_ws;
    float* xt   = (float*)((char*)d_ws + 256);
    float* agg  = (float*)d_out;

    hipMemsetAsync(d_out, 0, (size_t)N * 16 * sizeof(float), stream);
    hipLaunchKernelGGL(hgcn_k_detect, dim3(1), dim3(256), 0, stream, edge_src, E, flag);
    hipLaunchKernelGGL(hgcn_k1, dim3(1024), dim3(256), 0, stream,
                       x, weight, bias, xt, N);
    long long thr = E * 16;
    hipLaunchKernelGGL(hgcn_k2, dim3((unsigned)((thr + 255) / 256)), dim3(256), 0, stream,
                       edge_src, edge_dst, edge_w, xt, agg, E, flag);
    hipLaunchKernelGGL(hgcn_k3, dim3((unsigned)(((long long)N * 16 + 255) / 256)), dim3(256), 0, stream,
                       agg, N);
}

// Round 4
// 257.405 us; speedup vs baseline: 3.0291x; 1.2094x over previous
//
#include <hip/hip_runtime.h>
#include <math.h>

#define MIN_NORM 1e-15f
#define MAXN     0.996f          // (1 - 4e-3)/sqrt(c), c=1
#define ATC      0.9999999f      // artanh clip = 1 - 1e-7

__device__ __forceinline__ float fast_artanh(float v) {
    v = fminf(fmaxf(v, -ATC), ATC);
    return 0.5f * __logf((1.0f + v) / (1.0f - v));
}
__device__ __forceinline__ float fast_tanh(float xv) {
    float e2 = __expf(2.0f * xv);
    return (e2 - 1.0f) / (e2 + 1.0f);
}
__device__ __forceinline__ float reduce16(float v) {
    v += __shfl_xor(v, 1);
    v += __shfl_xor(v, 2);
    v += __shfl_xor(v, 4);
    v += __shfl_xor(v, 8);
    return v;
}

// ---- kernel 1: fused HypLinear + logmap0. One wave per row-GEMM, x in
// registers; Möbius tail batched 4 rows/wave (one row per 16-lane group). ----
__global__ __launch_bounds__(256) void hgcn_k1(
    const float* __restrict__ x, const float* __restrict__ weight,
    const float* __restrict__ bias, float* __restrict__ xt, int N)
{
    const int tid  = threadIdx.x;
    const int lane = tid & 63;
    const int wib  = tid >> 6;           // wave in block (0..3)
    const int k    = lane & 15;
    const int grp  = lane >> 4;          // 16-lane group (0..3)

    // W fragment in registers: wr[kk][jj] = W[kk][lane*8 + jj]
    float wr[16][8];
    const float* wp = weight + lane * 8;
#pragma unroll
    for (int kk = 0; kk < 16; ++kk) {
        float4 a = *(const float4*)(wp + kk * 512);
        float4 b = *(const float4*)(wp + kk * 512 + 4);
        wr[kk][0] = a.x; wr[kk][1] = a.y; wr[kk][2] = a.z; wr[kk][3] = a.w;
        wr[kk][4] = b.x; wr[kk][5] = b.y; wr[kk][6] = b.z; wr[kk][7] = b.w;
    }

    // hyp_bias = proj(expmap0(bias)) — replicated per 16-lane group
    float bb = bias[k];
    float b2 = reduce16(bb * bb);
    float bn = fmaxf(sqrtf(b2), MIN_NORM);
    float eb = fast_tanh(bn) * bb / bn;
    float e2 = reduce16(eb * eb);
    float en = fmaxf(sqrtf(e2), MIN_NORM);
    float hb = (en > MAXN) ? eb * (MAXN / en) : eb;
    float y2 = reduce16(hb * hb);

    const long long stride = (long long)gridDim.x * 4 * 4;   // rows per sweep
    long long base = ((long long)blockIdx.x * 4 + wib) * 4;  // 4 rows per wave

    float4 c0 = {0,0,0,0}, c1 = {0,0,0,0};
    if (base < N) {
        const float* xr = x + base * 512 + lane * 8;
        c0 = *(const float4*)(xr);
        c1 = *(const float4*)(xr + 4);
    }

    while (base < N) {
        float x2sel = 0.0f, mxsel = 0.0f;

#pragma unroll
        for (int p = 0; p < 4; ++p) {
            long long nrow = (p < 3) ? (base + p + 1) : (base + stride);
            float4 n0 = {0,0,0,0}, n1 = {0,0,0,0};
            if (nrow < N) {              // prefetch next row
                const float* xr = x + nrow * 512 + lane * 8;
                n0 = *(const float4*)(xr);
                n1 = *(const float4*)(xr + 4);
            }

            float xv[8] = {c0.x, c0.y, c0.z, c0.w, c1.x, c1.y, c1.z, c1.w};

            // ||x||^2 over all 64 lanes
            float pq = 0.0f;
#pragma unroll
            for (int jj = 0; jj < 8; ++jj) pq = fmaf(xv[jj], xv[jj], pq);
#pragma unroll
            for (int m = 1; m <= 32; m <<= 1) pq += __shfl_xor(pq, m);
            if (grp == p) x2sel = pq;

            // GEMM + value-halving butterfly (stage 1 fused with the FMAs)
            float v8[8];
            {
                const bool h = lane & 1;
#pragma unroll
                for (int i = 0; i < 8; ++i) {
                    float a0 = 0.0f, a1 = 0.0f;
#pragma unroll
                    for (int jj = 0; jj < 8; ++jj) {
                        a0 = fmaf(wr[2*i][jj],   xv[jj], a0);
                        a1 = fmaf(wr[2*i+1][jj], xv[jj], a1);
                    }
                    float keep = h ? a1 : a0;
                    float give = h ? a0 : a1;
                    v8[i] = keep + __shfl_xor(give, 1);
                }
            }
            float v4[4];
            {
                const bool h = lane & 2;
#pragma unroll
                for (int i = 0; i < 4; ++i) {
                    float keep = h ? v8[2*i+1] : v8[2*i];
                    float give = h ? v8[2*i]   : v8[2*i+1];
                    v4[i] = keep + __shfl_xor(give, 2);
                }
            }
            float v2[2];
            {
                const bool h = lane & 4;
#pragma unroll
                for (int i = 0; i < 2; ++i) {
                    float keep = h ? v4[2*i+1] : v4[2*i];
                    float give = h ? v4[2*i]   : v4[2*i+1];
                    v2[i] = keep + __shfl_xor(give, 4);
                }
            }
            float mx;
            {
                const bool h = lane & 8;
                float keep = h ? v2[1] : v2[0];
                float give = h ? v2[0] : v2[1];
                mx = keep + __shfl_xor(give, 8);
            }
            mx += __shfl_xor(mx, 16);
            mx += __shfl_xor(mx, 32);
            if (grp == p) mxsel = mx;

            c0 = n0; c1 = n1;
        }

        // ---- Möbius tail: each 16-lane group handles row (base+grp) ----
        float mx2 = reduce16(mxsel * mxsel);
        float xn  = fmaxf(sqrtf(x2sel), MIN_NORM);
        float mxn = fmaxf(sqrtf(mx2),   MIN_NORM);
        float res = fast_tanh(mxn / xn * fast_artanh(xn)) * mxsel / mxn;
        if (mx2 == 0.0f) res = 0.0f;
        // proj
        float rn2 = reduce16(res * res);
        float rn  = fmaxf(sqrtf(rn2), MIN_NORM);
        float mv  = (rn > MAXN) ? res * (MAXN / rn) : res;
        // mobius_add(mv, hyp_bias)
        float mv2 = reduce16(mv * mv);
        float xy  = reduce16(mv * hb);
        float num = (1.0f + 2.0f * xy + y2) * mv + (1.0f - mv2) * hb;
        float den = 1.0f + 2.0f * xy + mv2 * y2;
        float hq  = num / fmaxf(den, MIN_NORM);
        // proj
        float hn2 = reduce16(hq * hq);
        float hn  = fmaxf(sqrtf(hn2), MIN_NORM);
        float hp  = (hn > MAXN) ? hq * (MAXN / hn) : hq;
        // logmap0
        float hp2 = reduce16(hp * hp);
        float pn  = fmaxf(sqrtf(hp2), MIN_NORM);
        float xtv = fast_artanh(pn) * hp / pn;

        long long myrow = base + grp;
        if (myrow < N) xt[myrow * 16 + k] = xtv;   // 256B coalesced per wave

        base += stride;
    }
}

// ---------------- index width detection ----------------
__global__ void hgcn_k_detect(const void* srcp, long long E, int* flag)
{
    const int tid = threadIdx.x;
    if (tid == 0) *flag = 0;
    __syncthreads();
    long long n = E / 2; if (n > 4096) n = 4096;
    int bad = 0;
    const unsigned long long* p = (const unsigned long long*)srcp;
    for (long long i = tid; i < n; i += 256)
        if (p[i] >= (1ULL << 32)) bad = 1;
    if (bad) atomicOr(flag, 1);
}

// ---- kernel 2: edge scatter-add, 16 lanes/edge, persistent + 2-stage pipe ---
// 16 consecutive lanes hit one 64B-aligned destination line -> TCC line-merge.
__global__ __launch_bounds__(256) void hgcn_k2(
    const void* __restrict__ srcp, const void* __restrict__ dstp,
    const float* __restrict__ ew, const float* __restrict__ xt,
    float* __restrict__ agg, long long E, const int* __restrict__ flag)
{
    const int k = threadIdx.x & 15;
    const bool i32 = (*flag != 0);
    const long long slots = ((long long)gridDim.x * 256) >> 4;
    long long e = ((long long)blockIdx.x * 256 + threadIdx.x) >> 4;

    long long d0 = 0; float w0 = 0.0f, v0 = 0.0f;
    bool have = e < E;
    if (have) {
        long long s0;
        if (i32) { s0 = ((const int*)srcp)[e];       d0 = ((const int*)dstp)[e]; }
        else     { s0 = ((const long long*)srcp)[e]; d0 = ((const long long*)dstp)[e]; }
        w0 = ew[e];
        v0 = xt[s0 * 16 + k];
    }
    while (have) {
        long long en = e + slots;
        long long d1 = 0; float w1 = 0.0f, v1 = 0.0f;
        bool haven = en < E;
        if (haven) {                      // prefetch next edge
            long long s1;
            if (i32) { s1 = ((const int*)srcp)[en];       d1 = ((const int*)dstp)[en]; }
            else     { s1 = ((const long long*)srcp)[en]; d1 = ((const long long*)dstp)[en]; }
            w1 = ew[en];
            v1 = xt[s1 * 16 + k];
        }
        atomicAdd(&agg[d0 * 16 + k], w0 * v0);
        e = en; d0 = d1; w0 = w1; v0 = v1; have = haven;
    }
}

// ---------------- kernel 3: finalize in place on d_out -----------------------
__global__ __launch_bounds__(256) void hgcn_k3(float* __restrict__ out, int N)
{
    int gid = blockIdx.x * blockDim.x + threadIdx.x;
    int row = gid >> 4;
    if (row >= N) return;
    float u = out[(size_t)row * 16 + (gid & 15)];

    float un2 = reduce16(u * u);
    float un  = fmaxf(sqrtf(un2), MIN_NORM);
    float h1  = fast_tanh(un) * u / un;
    float n2  = reduce16(h1 * h1);
    float n1  = fmaxf(sqrtf(n2), MIN_NORM);
    float h1p = (n1 > MAXN) ? h1 * (MAXN / n1) : h1;
    float m2  = reduce16(h1p * h1p);
    float pn  = fmaxf(sqrtf(m2), MIN_NORM);
    float xt2 = fast_artanh(pn) * h1p / pn;
    float a2  = reduce16(xt2 * xt2);
    float an  = fmaxf(sqrtf(a2), MIN_NORM);
    float h2  = fast_tanh(an) * xt2 / an;
    float b2  = reduce16(h2 * h2);
    float bn  = fmaxf(sqrtf(b2), MIN_NORM);
    float h2p = (bn > MAXN) ? h2 * (MAXN / bn) : h2;
    float c2  = reduce16(h2p * h2p);
    float cn  = fmaxf(sqrtf(c2), MIN_NORM);
    out[(size_t)row * 16 + (gid & 15)] = fast_artanh(cn) * h2p / cn;
}

extern "C" void kernel_launch(void* const* d_in, const int* in_sizes, int n_in,
                              void* d_out, int out_size, void* d_ws, size_t ws_size,
                              hipStream_t stream)
{
    const float* x        = (const float*)d_in[0];
    const float* weight   = (const float*)d_in[1];
    const float* bias     = (const float*)d_in[2];
    const float* edge_w   = (const float*)d_in[3];
    const void*  edge_src = d_in[4];
    const void*  edge_dst = d_in[5];

    const int Kv = in_sizes[2];          // 16
    const int Dv = in_sizes[1] / Kv;     // 512
    const int N  = in_sizes[0] / Dv;     // 100000
    const long long E = in_sizes[3];     // 3200000

    int*   flag = (int*)d_ws;
    float* xt   = (float*)((char*)d_ws + 256);
    float* agg  = (float*)d_out;

    hipMemsetAsync(d_out, 0, (size_t)N * 16 * sizeof(float), stream);
    hipLaunchKernelGGL(hgcn_k_detect, dim3(1), dim3(256), 0, stream, edge_src, E, flag);
    hipLaunchKernelGGL(hgcn_k1, dim3(1024), dim3(256), 0, stream,
                       x, weight, bias, xt, N);
    hipLaunchKernelGGL(hgcn_k2, dim3(2048), dim3(256), 0, stream,
                       edge_src, edge_dst, edge_w, xt, agg, E, flag);
    hipLaunchKernelGGL(hgcn_k3, dim3((unsigned)(((long long)N * 16 + 255) / 256)), dim3(256), 0, stream,
                       agg, N);
}